// Round 1
// 125.987 us; speedup vs baseline: 1.0842x; 1.0842x over previous
//
#include <hip/hip_runtime.h>
#include <cstdint>

#define NNODES 10000
#define FDIM 128
#define MAXDEG 192
#define SLOTS 48                           // per-stripe slots (4*48 = 192)

typedef _Float16 h2v  __attribute__((ext_vector_type(2)));
typedef _Float16 f16x8 __attribute__((ext_vector_type(8)));
typedef float    f32x4 __attribute__((ext_vector_type(4)));

// Module-owned scratch (BSS, zero at load) — no d_ws dependence.
// g_cnt invariant: zero at entry to every kernel_launch (BSS on first call;
// gin_layer<1> re-zeroes its blocks' counters after last use every call).
// Row NNODES of g_xh/g_h1h is a SENTINEL ZERO row (never written): gather
// tails are padded to multiples of 4 edges by pointing at it.
__device__ __align__(16)  int      g_cnt[NNODES * 4];     // striped degree counters
__device__                int      g_bucket[NNODES * MAXDEG]; // stripe sub-lists
__device__ __align__(256) unsigned g_xh [(NNODES + 1) * FDIM / 2]; // x  fp16x2
__device__ __align__(256) unsigned g_h1h[(NNODES + 1) * FDIM / 2]; // h1 fp16x2
__device__ __align__(16)  unsigned g_wf[2 * 8192];        // W1/W2 pre-packed B-frags

__device__ inline h2v as_h2(unsigned u) { return __builtin_bit_cast(h2v, u); }
__device__ inline unsigned as_u(h2v v) { return __builtin_bit_cast(unsigned, v); }
__device__ inline unsigned pack_f16x2(float a, float b) {
  h2v v; v[0] = (_Float16)a; v[1] = (_Float16)b;
  return as_u(v);
}
__device__ inline void vadd4(uint4& a, const uint4& b) {   // 4x v_pk_add_f16
  a.x = as_u(as_h2(a.x) + as_h2(b.x));
  a.y = as_u(as_h2(a.y) + as_h2(b.y));
  a.z = as_u(as_h2(a.z) + as_h2(b.z));
  a.w = as_u(as_h2(a.w) + as_h2(b.w));
}

// ---------------- prep: bucket fill + x cast + W pre-pack -----------------
__global__ __launch_bounds__(256) void prep_kernel(
    const float* __restrict__ x, const int* __restrict__ ei,
    const float* __restrict__ w1, const float* __restrict__ w2,
    int E_, int EBLK, int CBLK) {
  const int bid = blockIdx.x;
  if (bid < EBLK) {
    int e = bid * 256 + threadIdx.x;
    if (e < E_) {
      int d = ei[E_ + e];                  // dst
      int s = ei[e];                       // src
      int st = e & 3;
      int p = atomicAdd(&g_cnt[d * 4 + st], 1);
      if (p < SLOTS) g_bucket[d * MAXDEG + st * SLOTS + p] = s;
    }
  } else if (bid < EBLK + CBLK) {
    int i = (bid - EBLK) * 256 + threadIdx.x;
    if (i < NNODES * FDIM / 2) {
      float2 v = *(const float2*)(x + 2 * (size_t)i);
      g_xh[i] = pack_f16x2(v.x, v.y);
    }
  } else {
    // pack W1/W2 into the exact MFMA B-fragment dword layout once.
    // Layout matches gin stage: entry s -> (nk = s>>6, sl = s&63),
    // n = nk>>2, kc = nk&3, kbase = kc*32 + (sl>>4)*8, f = n*16 + (sl&15).
    int idx = (bid - EBLK - CBLK) * 256 + threadIdx.x;  // 0..4095
    const float* w = (idx >= 2048) ? w2 : w1;
    int s = idx & 2047;
    int sl = s & 63, nk = s >> 6;
    int n = nk >> 2, kc = nk & 3;
    int kbase = kc * 32 + (sl >> 4) * 8;
    int f = n * 16 + (sl & 15);
    unsigned d0 = pack_f16x2(w[(size_t)(kbase + 0) * FDIM + f],
                             w[(size_t)(kbase + 1) * FDIM + f]);
    unsigned d1 = pack_f16x2(w[(size_t)(kbase + 2) * FDIM + f],
                             w[(size_t)(kbase + 3) * FDIM + f]);
    unsigned d2 = pack_f16x2(w[(size_t)(kbase + 4) * FDIM + f],
                             w[(size_t)(kbase + 5) * FDIM + f]);
    unsigned d3 = pack_f16x2(w[(size_t)(kbase + 6) * FDIM + f],
                             w[(size_t)(kbase + 7) * FDIM + f]);
    *(uint4*)(g_wf + (idx >> 11) * 8192 + 4 * s) = make_uint4(d0, d1, d2, d3);
  }
}

// ---------------- fused GIN layer: 16 nodes/block, 8-wave cooperative -----
// Block = 512 thr (8 waves) = 16 nodes (625 blocks x 16 = 10000 exactly).
// Phase 1 (NEW): wave w gathers nodes node0+2w, +1 with dwordx4 rows:
//   lane (quad q, m16) reads 16 B of row edge[4s+q] -> one wave-load
//   consumes 4 edges (1 KB). 4x fewer VMEM + bpermute instrs vs dword/lane;
//   fp16 add count conserved. Tails padded with sentinel zero row NNODES.
//   Quad partials folded by xor-16/xor-32 butterfly; lanes<16 write A row.
// Phase 2: wave w computes feature-tile n = w: 4 kchunks of
//   v_mfma_f32_16x16x32_f16 (A/B frag [idx=lane&15][k=(lane>>4)*8+j];
//   D col=lane&15(+16n), row=(lane>>4)*4+reg).
// MODE 0: relu -> g_h1h (packed fp16x2). MODE 1: log_softmax -> out_g (fp32)
//         + re-zero this block's stripe counters.
template <int MODE>
__global__ __launch_bounds__(512) void gin_layer_kernel(
    const float* __restrict__ b,
    float* __restrict__ out_g) {
  const unsigned* __restrict__ xh = (MODE == 0) ? g_xh : g_h1h;

  __shared__ __align__(16) unsigned wl[8192];   // 32 KB W B-frags (epilogue reuse)
  __shared__ __align__(16) unsigned al[16 * 68]; // A tile: 16 x 64 dwords (+4 pad)

  const int tid = threadIdx.x;
  const int wave = tid >> 6, lane = tid & 63;
  const int quad = lane >> 4, m16 = lane & 15;
  const int node0 = blockIdx.x * 16;

  // ---- stage W: straight dwordx4 copy of pre-packed fragments ----
  {
    const uint4* wf4 = (const uint4*)(g_wf + (MODE ? 8192 : 0));
    uint4* wl4 = (uint4*)wl;
#pragma unroll
    for (int it = 0; it < 4; ++it) wl4[tid + it * 512] = wf4[tid + it * 512];
  }

  // ---- phase 1 prologue: self rows + stripe counters for my 2 nodes ----
  const int myn0 = node0 + wave * 2;
  uint4 self4[2];
  int o1[2], o2[2], o3[2], dgg[2];
#pragma unroll
  for (int i = 0; i < 2; ++i) {
    self4[i] = *(const uint4*)(xh + (size_t)(myn0 + i) * 64 + (m16 << 2));
    int4 c = *(const int4*)(g_cnt + (myn0 + i) * 4);
    int a = (c.x > SLOTS) ? SLOTS : c.x;
    int bq = (c.y > SLOTS) ? SLOTS : c.y;
    int cq = (c.z > SLOTS) ? SLOTS : c.z;
    int dq = (c.w > SLOTS) ? SLOTS : c.w;
    o1[i] = a; o2[i] = a + bq; o3[i] = a + bq + cq; dgg[i] = a + bq + cq + dq;
  }

  for (int i = 0; i < 2; ++i) {
    h2v a0 = as_h2(0u), a1 = as_h2(0u), a2 = as_h2(0u), a3 = as_h2(0u);
    const int deg = dgg[i];
    const int* nb = g_bucket + (size_t)(myn0 + i) * MAXDEG;
    for (int p = 0; p < deg; p += 64) {
      int n = deg - p; if (n > 64) n = 64;
      int myedge = NNODES;                 // sentinel zero row for padding
      if (lane < n) {                      // stripe-select index fetch
        int g = p + lane;
        int base = 0;
        if (g >= o1[i]) base = o1[i];
        if (g >= o2[i]) base = o2[i];
        if (g >= o3[i]) base = o3[i];
        int st = (g >= o1[i]) + (g >= o2[i]) + (g >= o3[i]);
        myedge = nb[st * SLOTS + (g - base)];
      }
      const int nst = (n + 3) >> 2;        // 4-edge steps (sentinel-padded)
      int s = 0;
      for (; s + 8 <= nst; s += 8) {       // 8 dwordx4 (=32 edges) in flight
        uint4 t[8];
#pragma unroll
        for (int k = 0; k < 8; ++k) {
          int e = __builtin_amdgcn_ds_bpermute((((s + k) << 2) | quad) << 2, myedge);
          t[k] = *(const uint4*)(xh + (unsigned)((e << 6) | (m16 << 2)));
        }
#pragma unroll
        for (int st2 = 1; st2 < 8; st2 <<= 1)
#pragma unroll
          for (int k = 0; k < 8; k += 2 * st2) vadd4(t[k], t[k + st2]);
        a0 += as_h2(t[0].x); a1 += as_h2(t[0].y);
        a2 += as_h2(t[0].z); a3 += as_h2(t[0].w);
      }
      if (s + 4 <= nst) {                  // 4-step batch (16 edges)
        uint4 t[4];
#pragma unroll
        for (int k = 0; k < 4; ++k) {
          int e = __builtin_amdgcn_ds_bpermute((((s + k) << 2) | quad) << 2, myedge);
          t[k] = *(const uint4*)(xh + (unsigned)((e << 6) | (m16 << 2)));
        }
        vadd4(t[0], t[1]); vadd4(t[2], t[3]); vadd4(t[0], t[2]);
        a0 += as_h2(t[0].x); a1 += as_h2(t[0].y);
        a2 += as_h2(t[0].z); a3 += as_h2(t[0].w);
        s += 4;
      }
      for (; s < nst; ++s) {               // <=3 single steps
        int e = __builtin_amdgcn_ds_bpermute(((s << 2) | quad) << 2, myedge);
        uint4 t = *(const uint4*)(xh + (unsigned)((e << 6) | (m16 << 2)));
        a0 += as_h2(t.x); a1 += as_h2(t.y); a2 += as_h2(t.z); a3 += as_h2(t.w);
      }
    }
    // fold the 4 quad partials (xor-16 then xor-32 butterfly; all lanes valid)
    int r;
    r = __shfl_xor((int)as_u(a0), 16, 64); a0 += as_h2((unsigned)r);
    r = __shfl_xor((int)as_u(a0), 32, 64); a0 += as_h2((unsigned)r);
    r = __shfl_xor((int)as_u(a1), 16, 64); a1 += as_h2((unsigned)r);
    r = __shfl_xor((int)as_u(a1), 32, 64); a1 += as_h2((unsigned)r);
    r = __shfl_xor((int)as_u(a2), 16, 64); a2 += as_h2((unsigned)r);
    r = __shfl_xor((int)as_u(a2), 32, 64); a2 += as_h2((unsigned)r);
    r = __shfl_xor((int)as_u(a3), 16, 64); a3 += as_h2((unsigned)r);
    r = __shfl_xor((int)as_u(a3), 32, 64); a3 += as_h2((unsigned)r);
    // (1+eps)*x self term, added once after the fold
    a0 += as_h2(self4[i].x); a1 += as_h2(self4[i].y);
    a2 += as_h2(self4[i].z); a3 += as_h2(self4[i].w);
    if (quad == 0)
      *(uint4*)(al + (wave * 2 + i) * 68 + (m16 << 2)) =
          make_uint4(as_u(a0), as_u(a1), as_u(a2), as_u(a3));
  }
  __syncthreads();                         // A + W visible to all waves

  // ---- phase 2: MFMA, ntile n = wave ----
  uint4 af[4];
#pragma unroll
  for (int kc = 0; kc < 4; ++kc)
    af[kc] = *(const uint4*)(al + m16 * 68 + kc * 16 + quad * 4);

  const int n = wave;
  const float bb = b[n * 16 + m16];
  f32x4 acc = {0.f, 0.f, 0.f, 0.f};
#pragma unroll
  for (int kc = 0; kc < 4; ++kc) {
    uint4 bf = *(const uint4*)(wl + ((n * 4 + kc) * 64 + lane) * 4);
    acc = __builtin_amdgcn_mfma_f32_16x16x32_f16(
            __builtin_bit_cast(f16x8, af[kc]),
            __builtin_bit_cast(f16x8, bf), acc, 0, 0, 0);
  }
  __syncthreads();                         // all MFMA reads of wl/al done

  // ---- epilogue (wl reused as scratch) ----
  if (MODE == 0) {
    // relu + fp16 pack: rows padded to 136 halves for bank spread
    _Float16* ch = (_Float16*)wl;
    const int f = n * 16 + m16;
#pragma unroll
    for (int reg = 0; reg < 4; ++reg)
      ch[(quad * 4 + reg) * 136 + f] = (_Float16)fmaxf(acc[reg] + bb, 0.f);
    __syncthreads();
    const int row = tid >> 5, c2 = (tid & 31) * 2;
    uint2 v = *(const uint2*)(wl + row * 68 + c2);
    *(uint2*)(&g_h1h[(size_t)(node0 + row) * 64 + c2]) = v;
  } else {
    // log_softmax: vals to LDS fp32 (rows padded to 132 floats)
    float* cf = (float*)wl;
    const int f = n * 16 + m16;
#pragma unroll
    for (int reg = 0; reg < 4; ++reg)
      cf[(quad * 4 + reg) * 132 + f] = acc[reg] + bb;
    __syncthreads();
    const int row = tid >> 5, li = tid & 31;   // 32 threads per row
    const float* base = cf + row * 132 + li * 4;
    float4 a4 = *(const float4*)(base);
    float mx = fmaxf(fmaxf(a4.x, a4.y), fmaxf(a4.z, a4.w));
#pragma unroll
    for (int off = 16; off >= 1; off >>= 1)
      mx = fmaxf(mx, __shfl_xor(mx, off, 64));   // within 32-lane half-wave
    float s = (__expf(a4.x - mx) + __expf(a4.y - mx))
            + (__expf(a4.z - mx) + __expf(a4.w - mx));
#pragma unroll
    for (int off = 16; off >= 1; off >>= 1)
      s += __shfl_xor(s, off, 64);
    const float ls = mx + __logf(s);
    float* orow = out_g + (size_t)(node0 + row) * FDIM + li * 4;
    *(float4*)(orow) = make_float4(a4.x - ls, a4.y - ls, a4.z - ls, a4.w - ls);
    // restore counter invariant: this block's 16 nodes x 4 stripes
    if (tid < 64) g_cnt[node0 * 4 + tid] = 0;
  }
}

extern "C" void kernel_launch(void* const* d_in, const int* in_sizes, int n_in,
                              void* d_out, int out_size, void* d_ws, size_t ws_size,
                              hipStream_t stream) {
  const float* x  = (const float*)d_in[0];
  const int*   ei = (const int*)d_in[1];     // int64 in reference -> int32 here
  const float* w1 = (const float*)d_in[2];
  const float* b1 = (const float*)d_in[3];
  const float* w2 = (const float*)d_in[4];
  const float* b2 = (const float*)d_in[5];
  float* out = (float*)d_out;

  const int E_ = in_sizes[1] / 2;
  const int EBLK = (E_ + 255) / 256;
  const int CBLK = (NNODES * FDIM / 2 + 255) / 256;
  const int WBLK = 16;                     // 4096 threads: 2x2048 W-frag entries

  // ---- prep: bucket fill + cast + W pre-pack (counters zero by invariant) ----
  prep_kernel<<<EBLK + CBLK + WBLK, 256, 0, stream>>>(x, ei, w1, w2, E_, EBLK, CBLK);

  // ---- fused layers: 625 blocks x 8 waves x 2 nodes = 10000 exactly ----
  gin_layer_kernel<0><<<625, 512, 0, stream>>>(b1, nullptr);
  gin_layer_kernel<1><<<625, 512, 0, stream>>>(b2, out);
}